// Round 2
// baseline (253.477 us; speedup 1.0000x reference)
//
#include <hip/hip_runtime.h>
#include <hip/hip_bf16.h>

// Problem: out[4096,1000] = core[4096,4096] @ weights[1000,4096]^T, fp32.
// Strategy: split fp32 into bf16 hi+lo, 3-term MFMA GEMM (Ah*Wh + Al*Wh + Ah*Wl)
// for ~fp32 accuracy at bf16-MFMA rates.

#define M_DIM 4096
#define K_DIM 4096
#define N_CLS 1000
#define N_PAD 1024

#define BM 128
#define BN 64
#define BK 32

typedef short bf16x8 __attribute__((ext_vector_type(8)));
typedef float f32x4 __attribute__((ext_vector_type(4)));

// ---------- fp32 -> bf16 hi/lo split helpers ----------
__device__ inline unsigned short f32_to_bf16_rne(float x) {
    unsigned int u = __float_as_uint(x);
    unsigned int r = (u + 0x7fffu + ((u >> 16) & 1u)) >> 16;
    return (unsigned short)r;
}
__device__ inline float bf16u_to_f32(unsigned short h) {
    return __uint_as_float(((unsigned int)h) << 16);
}

// Split n_dst4 float4-chunks: src chunks < n_src4 are split, rest write zeros (padding).
__global__ void split_kernel(const float* __restrict__ in,
                             unsigned short* __restrict__ hi,
                             unsigned short* __restrict__ lo,
                             int n_src4, int n_dst4) {
    int i = blockIdx.x * blockDim.x + threadIdx.x;
    if (i >= n_dst4) return;
    float f[4] = {0.f, 0.f, 0.f, 0.f};
    if (i < n_src4) {
        float4 v = ((const float4*)in)[i];
        f[0] = v.x; f[1] = v.y; f[2] = v.z; f[3] = v.w;
    }
    ushort4 h, l;
    unsigned short hh[4], ll[4];
#pragma unroll
    for (int j = 0; j < 4; ++j) {
        unsigned short bh = f32_to_bf16_rne(f[j]);
        float xh = bf16u_to_f32(bh);
        unsigned short bl = f32_to_bf16_rne(f[j] - xh);
        hh[j] = bh; ll[j] = bl;
    }
    h.x = hh[0]; h.y = hh[1]; h.z = hh[2]; h.w = hh[3];
    l.x = ll[0]; l.y = ll[1]; l.z = ll[2]; l.w = ll[3];
    ((ushort4*)hi)[i] = h;
    ((ushort4*)lo)[i] = l;
}

// ---------- async global->LDS (width 16, literal size) ----------
__device__ inline void load_lds16(const unsigned short* g, unsigned short* l) {
    __builtin_amdgcn_global_load_lds(
        (const __attribute__((address_space(1))) unsigned int*)(const void*)g,
        (__attribute__((address_space(3))) unsigned int*)(void*)l, 16, 0, 0);
}

// ---------- 3-term bf16 MFMA GEMM ----------
// Grid: (N_PAD/BN, M_DIM/BM) = (16, 32). Block: 256 threads = 4 waves (2x2).
// Each wave owns a 64x32 output sub-tile: 4x2 frags of 16x16.
__launch_bounds__(256, 2)
__global__ void gemm3_kernel(const unsigned short* __restrict__ Ah,
                             const unsigned short* __restrict__ Al,
                             const unsigned short* __restrict__ Wh,
                             const unsigned short* __restrict__ Wl,
                             float* __restrict__ out) {
    __shared__ __align__(16) unsigned short sAh[BM * BK];
    __shared__ __align__(16) unsigned short sAl[BM * BK];
    __shared__ __align__(16) unsigned short sBh[BN * BK];
    __shared__ __align__(16) unsigned short sBl[BN * BK];

    const int tid  = threadIdx.x;
    const int lane = tid & 63;
    const int wid  = tid >> 6;
    const int wr   = wid >> 1;   // 0..1
    const int wc   = wid & 1;    // 0..1
    const int brow = blockIdx.y * BM;
    const int bcol = blockIdx.x * BN;

    f32x4 acc[4][2] = {};

    // Staging geometry: 16B chunk c covers tile row c>>2, cols (c&3)*8 .. +8.
    // A tile has 512 chunks (threads do c=tid and c=tid+256); B tile has 256 (c=tid).
    const int c_row = tid >> 2;
    const int c_col = (tid & 3) * 8;
    const size_t a_base0 = (size_t)(brow + c_row) * K_DIM + c_col;
    const size_t a_base1 = (size_t)(brow + c_row + 64) * K_DIM + c_col;
    const size_t b_base  = (size_t)(bcol + c_row) * K_DIM + c_col;

    const int lr = lane & 15;        // frag row/col within 16
    const int lk = (lane >> 4) * 8;  // k-offset within 32

    for (int k0 = 0; k0 < K_DIM; k0 += BK) {
        // stage next tiles (linear LDS dest, lane-ordered — required by global_load_lds)
        load_lds16(Ah + a_base0 + k0, &sAh[(size_t)tid * 8]);
        load_lds16(Ah + a_base1 + k0, &sAh[(size_t)(tid + 256) * 8]);
        load_lds16(Al + a_base0 + k0, &sAl[(size_t)tid * 8]);
        load_lds16(Al + a_base1 + k0, &sAl[(size_t)(tid + 256) * 8]);
        load_lds16(Wh + b_base + k0, &sBh[(size_t)tid * 8]);
        load_lds16(Wl + b_base + k0, &sBl[(size_t)tid * 8]);
        __syncthreads();  // drains vmcnt -> tiles resident

        bf16x8 ah[4], al[4], bh[2], bl[2];
#pragma unroll
        for (int m = 0; m < 4; ++m) {
            ah[m] = *(const bf16x8*)&sAh[(wr * 64 + m * 16 + lr) * BK + lk];
            al[m] = *(const bf16x8*)&sAl[(wr * 64 + m * 16 + lr) * BK + lk];
        }
#pragma unroll
        for (int n = 0; n < 2; ++n) {
            bh[n] = *(const bf16x8*)&sBh[(wc * 32 + n * 16 + lr) * BK + lk];
            bl[n] = *(const bf16x8*)&sBl[(wc * 32 + n * 16 + lr) * BK + lk];
        }

#pragma unroll
        for (int m = 0; m < 4; ++m) {
#pragma unroll
            for (int n = 0; n < 2; ++n) {
                acc[m][n] = __builtin_amdgcn_mfma_f32_16x16x32_bf16(ah[m], bh[n], acc[m][n], 0, 0, 0);
                acc[m][n] = __builtin_amdgcn_mfma_f32_16x16x32_bf16(al[m], bh[n], acc[m][n], 0, 0, 0);
                acc[m][n] = __builtin_amdgcn_mfma_f32_16x16x32_bf16(ah[m], bl[n], acc[m][n], 0, 0, 0);
            }
        }
        __syncthreads();  // all waves done reading before next overwrite
    }

    // Epilogue: C/D layout col=lane&15, row=(lane>>4)*4+j (verified m89/m91)
#pragma unroll
    for (int m = 0; m < 4; ++m) {
#pragma unroll
        for (int n = 0; n < 2; ++n) {
#pragma unroll
            for (int j = 0; j < 4; ++j) {
                int row = brow + wr * 64 + m * 16 + (lane >> 4) * 4 + j;
                int col = bcol + wc * 32 + n * 16 + lr;
                if (col < N_CLS)
                    out[(size_t)row * N_CLS + col] = acc[m][n][j];
            }
        }
    }
}

// ---------- fp32 fallback (only if ws too small) ----------
__global__ void fallback_gemm(const float* __restrict__ A, const float* __restrict__ W,
                              float* __restrict__ out) {
    __shared__ float sA[16][17];
    __shared__ float sW[16][17];
    int tx = threadIdx.x, ty = threadIdx.y;
    int row  = blockIdx.y * 16 + ty;
    int wrow = blockIdx.x * 16 + ty;
    float acc = 0.f;
    for (int k0 = 0; k0 < K_DIM; k0 += 16) {
        sA[ty][tx] = A[(size_t)row * K_DIM + k0 + tx];
        sW[ty][tx] = (wrow < N_CLS) ? W[(size_t)wrow * K_DIM + k0 + tx] : 0.f;
        __syncthreads();
#pragma unroll
        for (int kk = 0; kk < 16; ++kk) acc += sA[ty][kk] * sW[tx][kk];
        __syncthreads();
    }
    int col = blockIdx.x * 16 + tx;
    if (col < N_CLS) out[(size_t)row * N_CLS + col] = acc;
}

extern "C" void kernel_launch(void* const* d_in, const int* in_sizes, int n_in,
                              void* d_out, int out_size, void* d_ws, size_t ws_size,
                              hipStream_t stream) {
    const float* core    = (const float*)d_in[0];   // [4096][4096]
    const float* weights = (const float*)d_in[1];   // [1000][4096]
    float* out = (float*)d_out;                     // [4096][1000]

    const size_t A_ELEMS = (size_t)M_DIM * K_DIM;   // 16,777,216
    const size_t W_SRC   = (size_t)N_CLS * K_DIM;   //  4,096,000
    const size_t W_ELEMS = (size_t)N_PAD * K_DIM;   //  4,194,304
    const size_t need = (2 * A_ELEMS + 2 * W_ELEMS) * sizeof(unsigned short); // 80 MiB

    if (ws_size < need) {
        dim3 blk(16, 16), grd((N_CLS + 15) / 16, M_DIM / 16);
        fallback_gemm<<<grd, blk, 0, stream>>>(core, weights, out);
        return;
    }

    unsigned short* Ah = (unsigned short*)d_ws;
    unsigned short* Al = Ah + A_ELEMS;
    unsigned short* Wh = Al + A_ELEMS;
    unsigned short* Wl = Wh + W_ELEMS;

    // Split passes (ws re-poisoned every launch -> must rewrite fully each call)
    split_kernel<<<(int)(A_ELEMS / 4 / 256), 256, 0, stream>>>(
        core, Ah, Al, (int)(A_ELEMS / 4), (int)(A_ELEMS / 4));
    split_kernel<<<(int)(W_ELEMS / 4 / 256), 256, 0, stream>>>(
        weights, Wh, Wl, (int)(W_SRC / 4), (int)(W_ELEMS / 4));

    dim3 grid(N_PAD / BN, M_DIM / BM);  // (16, 32) = 512 blocks
    gemm3_kernel<<<grid, 256, 0, stream>>>(Ah, Al, Wh, Wl, out);
}

// Round 3
// 247.239 us; speedup vs baseline: 1.0252x; 1.0252x over previous
//
#include <hip/hip_runtime.h>
#include <hip/hip_bf16.h>

// out[4096,1000] = core[4096,4096] @ weights[1000,4096]^T, fp32.
// bf16 hi/lo split, 3-term MFMA GEMM (Ah*Wh + Al*Wh + Ah*Wl).
// R3: 128x128 tile, double-buffered LDS (1 barrier/K-step), XOR-swizzled LDS
//     (pre-swizzled global source, linear global_load_lds dest), split-K x2
//     with f32 atomics, XCD-chunked block swizzle, fused split kernel.

#define M_DIM 4096
#define K_DIM 4096
#define N_CLS 1000
#define N_PAD 1024

#define BM 128
#define BN 128
#define BK 32
#define KSPLIT 2

typedef short bf16x8 __attribute__((ext_vector_type(8)));
typedef float f32x4 __attribute__((ext_vector_type(4)));
typedef unsigned short ushort8 __attribute__((ext_vector_type(8)));

__device__ inline unsigned short f32_to_bf16_rne(float x) {
    unsigned int u = __float_as_uint(x);
    unsigned int r = (u + 0x7fffu + ((u >> 16) & 1u)) >> 16;
    return (unsigned short)r;
}
__device__ inline float bf16u_to_f32(unsigned short h) {
    return __uint_as_float(((unsigned int)h) << 16);
}

// ---------- zero-init of out (needed: atomics accumulate, d_out poisoned) ----
__global__ void zero_out_kernel(float4* __restrict__ out4, int n4) {
    int i = blockIdx.x * blockDim.x + threadIdx.x;
    if (i < n4) out4[i] = make_float4(0.f, 0.f, 0.f, 0.f);
}

// ---------- fused split: core -> Ah/Al, weights -> Wh/Wl (padded) ----------
// Each logical chunk = 8 floats (32B in, 16B hi + 16B lo out). Grid-stride.
__global__ void split_fused(const float* __restrict__ core,
                            const float* __restrict__ wts,
                            unsigned short* __restrict__ Ah,
                            unsigned short* __restrict__ Al,
                            unsigned short* __restrict__ Wh,
                            unsigned short* __restrict__ Wl,
                            int na8, int nw8, int w_src) {
    int total = na8 + nw8;
    for (int i = blockIdx.x * blockDim.x + threadIdx.x; i < total;
         i += gridDim.x * blockDim.x) {
        const float* src;
        unsigned short *dh, *dl;
        bool valid;
        if (i < na8) {
            src = core + (size_t)i * 8;
            dh = Ah + (size_t)i * 8; dl = Al + (size_t)i * 8;
            valid = true;
        } else {
            int j = i - na8;
            src = wts + (size_t)j * 8;
            dh = Wh + (size_t)j * 8; dl = Wl + (size_t)j * 8;
            valid = (j * 8 < w_src);   // w_src % 8 == 0, no partial chunks
        }
        float f[8] = {0, 0, 0, 0, 0, 0, 0, 0};
        if (valid) {
            float4 v0 = ((const float4*)src)[0];
            float4 v1 = ((const float4*)src)[1];
            f[0] = v0.x; f[1] = v0.y; f[2] = v0.z; f[3] = v0.w;
            f[4] = v1.x; f[5] = v1.y; f[6] = v1.z; f[7] = v1.w;
        }
        ushort8 h, l;
#pragma unroll
        for (int j = 0; j < 8; ++j) {
            unsigned short bh = f32_to_bf16_rne(f[j]);
            h[j] = bh;
            l[j] = f32_to_bf16_rne(f[j] - bf16u_to_f32(bh));
        }
        *(ushort8*)dh = h;
        *(ushort8*)dl = l;
    }
}

// ---------- async global->LDS, width 16 (literal) ----------
__device__ inline void load_lds16(const unsigned short* g, unsigned short* l) {
    __builtin_amdgcn_global_load_lds(
        (const __attribute__((address_space(1))) unsigned int*)(const void*)g,
        (__attribute__((address_space(3))) unsigned int*)(void*)l, 16, 0, 0);
}

// ---------- 3-term GEMM, 128x128 tile, dbuf, swizzled LDS, split-K ----------
// LDS per buffer: sA[128][64] bf16 (cols 0-31 Ah k-window, 32-63 Al), sB same.
// Swizzle: 16B chunk at (row r, logical chunk c in 0..7) stored at slot
// (r, c ^ (r&7)). Written via pre-swizzled global SOURCE (linear lds dest,
// rule: both-sides-or-neither), read with the same XOR.
__launch_bounds__(256, 2)
__global__ void gemm3_kernel(const unsigned short* __restrict__ Ah,
                             const unsigned short* __restrict__ Al,
                             const unsigned short* __restrict__ Wh,
                             const unsigned short* __restrict__ Wl,
                             float* __restrict__ out) {
    __shared__ __align__(16) unsigned short sA[2][BM * 64];
    __shared__ __align__(16) unsigned short sB[2][BN * 64];

    const int tid  = threadIdx.x;
    const int lane = tid & 63;
    const int wid  = tid >> 6;
    const int wr   = wid >> 1;   // 0..1 (row half)
    const int wc   = wid & 1;    // 0..1 (col half)

    // XCD-chunked bijective swizzle: 512 blocks, 64 consecutive per XCD.
    int bid = blockIdx.x;
    int swz = (bid & 7) * 64 + (bid >> 3);
    const int colb = swz & 7;          // 8 col-blocks  (fastest -> A-panel L2 reuse)
    const int ks   = (swz >> 3) & 1;   // K-split slice
    const int rowb = swz >> 4;         // 32 row-blocks
    const int brow = rowb * BM;
    const int bcol = colb * BN;
    const int kbeg = ks * (K_DIM / KSPLIT);
    const int NT   = (K_DIM / KSPLIT) / BK;   // 64 K-steps

    // Staging: 1024 16B chunks per tile, 4 per thread. Dest slot s is LINEAR
    // (wave-uniform base + lane*16); source address carries the swizzle.
    const unsigned short* srcA[4];
    const unsigned short* srcB[4];
    int dstOff[4];
#pragma unroll
    for (int i = 0; i < 4; ++i) {
        int s = tid + 256 * i;          // 0..1023
        int r = s >> 3;                 // dest row
        int clog = (s & 7) ^ (r & 7);   // logical chunk stored at this slot
        dstOff[i] = s * 8;              // ushort offset (16B chunks)
        if (clog < 4) {
            srcA[i] = Ah + (size_t)(brow + r) * K_DIM + kbeg + clog * 8;
            srcB[i] = Wh + (size_t)(bcol + r) * K_DIM + kbeg + clog * 8;
        } else {
            srcA[i] = Al + (size_t)(brow + r) * K_DIM + kbeg + (clog - 4) * 8;
            srcB[i] = Wl + (size_t)(bcol + r) * K_DIM + kbeg + (clog - 4) * 8;
        }
    }

    f32x4 acc[4][4] = {};

    // read-side swizzle constants: row&7 == lr&7 for all frags (m*16, wr*64 = 0 mod 8)
    const int lr = lane & 15;
    const int hk = lane >> 4;                 // k-chunk 0..3 (8 bf16 each)
    const int xh = ((hk ^ (lr & 7)) * 8);     // Ah/Wh chunk offset (ushorts)
    const int xl = xh ^ 32;                   // Al/Wl: chunk^4 -> offset^32

#define STAGE(buf, koff)                                            \
    {                                                               \
        _Pragma("unroll")                                           \
        for (int i = 0; i < 4; ++i)                                 \
            load_lds16(srcA[i] + (koff), &sA[buf][dstOff[i]]);      \
        _Pragma("unroll")                                           \
        for (int i = 0; i < 4; ++i)                                 \
            load_lds16(srcB[i] + (koff), &sB[buf][dstOff[i]]);      \
    }

    STAGE(0, 0);
    __syncthreads();                    // vmcnt(0) drain: buf0 resident
    int cur = 0;

    for (int t = 0; t < NT; ++t) {
        if (t + 1 < NT) STAGE(cur ^ 1, (t + 1) * BK);   // prefetch next tile

        bf16x8 ah[4], al[4], bh[4], bl[4];
#pragma unroll
        for (int m = 0; m < 4; ++m) {
            int r = wr * 64 + m * 16 + lr;
            ah[m] = *(const bf16x8*)&sA[cur][r * 64 + xh];
            al[m] = *(const bf16x8*)&sA[cur][r * 64 + xl];
        }
#pragma unroll
        for (int n = 0; n < 4; ++n) {
            int r = wc * 64 + n * 16 + lr;
            bh[n] = *(const bf16x8*)&sB[cur][r * 64 + xh];
            bl[n] = *(const bf16x8*)&sB[cur][r * 64 + xl];
        }

#pragma unroll
        for (int m = 0; m < 4; ++m) {
#pragma unroll
            for (int n = 0; n < 4; ++n) {
                acc[m][n] = __builtin_amdgcn_mfma_f32_16x16x32_bf16(ah[m], bh[n], acc[m][n], 0, 0, 0);
                acc[m][n] = __builtin_amdgcn_mfma_f32_16x16x32_bf16(al[m], bh[n], acc[m][n], 0, 0, 0);
                acc[m][n] = __builtin_amdgcn_mfma_f32_16x16x32_bf16(ah[m], bl[n], acc[m][n], 0, 0, 0);
            }
        }
        __syncthreads();   // drains prefetch vmcnt + all waves done reading cur
        cur ^= 1;
    }

    // Epilogue: C/D layout col=lane&15, row=(lane>>4)*4+j; split-K -> atomics.
#pragma unroll
    for (int m = 0; m < 4; ++m) {
        int r0 = brow + wr * 64 + m * 16 + hk * 4;
#pragma unroll
        for (int n = 0; n < 4; ++n) {
            int c = bcol + wc * 64 + n * 16 + lr;
            if (c < N_CLS) {
#pragma unroll
                for (int j = 0; j < 4; ++j)
                    atomicAdd(&out[(size_t)(r0 + j) * N_CLS + c], acc[m][n][j]);
            }
        }
    }
#undef STAGE
}

// ---------- fp32 fallback (only if ws too small) ----------
__global__ void fallback_gemm(const float* __restrict__ A, const float* __restrict__ W,
                              float* __restrict__ out) {
    __shared__ float sA[16][17];
    __shared__ float sW[16][17];
    int tx = threadIdx.x, ty = threadIdx.y;
    int row  = blockIdx.y * 16 + ty;
    int wrow = blockIdx.x * 16 + ty;
    float acc = 0.f;
    for (int k0 = 0; k0 < K_DIM; k0 += 16) {
        sA[ty][tx] = A[(size_t)row * K_DIM + k0 + tx];
        sW[ty][tx] = (wrow < N_CLS) ? W[(size_t)wrow * K_DIM + k0 + tx] : 0.f;
        __syncthreads();
#pragma unroll
        for (int kk = 0; kk < 16; ++kk) acc += sA[ty][kk] * sW[tx][kk];
        __syncthreads();
    }
    int col = blockIdx.x * 16 + tx;
    if (col < N_CLS) out[(size_t)row * N_CLS + col] = acc;
}

extern "C" void kernel_launch(void* const* d_in, const int* in_sizes, int n_in,
                              void* d_out, int out_size, void* d_ws, size_t ws_size,
                              hipStream_t stream) {
    const float* core    = (const float*)d_in[0];   // [4096][4096]
    const float* weights = (const float*)d_in[1];   // [1000][4096]
    float* out = (float*)d_out;                     // [4096][1000]

    const size_t A_ELEMS = (size_t)M_DIM * K_DIM;   // 16,777,216
    const size_t W_SRC   = (size_t)N_CLS * K_DIM;   //  4,096,000
    const size_t W_ELEMS = (size_t)N_PAD * K_DIM;   //  4,194,304
    const size_t need = (2 * A_ELEMS + 2 * W_ELEMS) * sizeof(unsigned short); // 80 MiB

    if (ws_size < need) {
        dim3 blk(16, 16), grd((N_CLS + 15) / 16, M_DIM / 16);
        fallback_gemm<<<grd, blk, 0, stream>>>(core, weights, out);
        return;
    }

    unsigned short* Ah = (unsigned short*)d_ws;
    unsigned short* Al = Ah + A_ELEMS;
    unsigned short* Wh = Al + A_ELEMS;
    unsigned short* Wl = Wh + W_ELEMS;

    // 1) zero out (atomic accumulation target; d_out is poisoned each launch)
    int n4 = (M_DIM * N_CLS) / 4;                    // 1,024,000
    zero_out_kernel<<<(n4 + 255) / 256, 256, 0, stream>>>((float4*)out, n4);

    // 2) split both inputs in one grid-stride kernel
    int na8 = (int)(A_ELEMS / 8);                    // 2,097,152
    int nw8 = (int)(W_ELEMS / 8);                    //   524,288
    split_fused<<<2048, 256, 0, stream>>>(core, weights, Ah, Al, Wh, Wl,
                                          na8, nw8, (int)W_SRC);

    // 3) GEMM: 512 blocks = (8 col) x (32 row) x (2 k-slices)
    gemm3_kernel<<<(N_PAD / BN) * (M_DIM / BM) * KSPLIT, 256, 0, stream>>>(
        Ah, Al, Wh, Wl, out);
}

// Round 6
// 224.713 us; speedup vs baseline: 1.1280x; 1.1002x over previous
//
#include <hip/hip_runtime.h>
#include <hip/hip_bf16.h>

// out[4096,1000] = core[4096,4096] @ weights[1000,4096]^T, fp32.
// R4: single-term f16 GEMM (error ~0.07 abs << 1.0 threshold).
//     Proven 2ph/128x128/XOR-swizzle structure from R3, KSPLIT=4 (4 blocks/CU),
//     A+B share one 128B-row LDS buffer (keeps the measured-0-conflict pattern).

#define M_DIM 4096
#define K_DIM 4096
#define N_CLS 1000
#define N_PAD 1024

#define BM 128
#define BN 128
#define BK 32
#define KSPLIT 4

typedef _Float16 f16x8 __attribute__((ext_vector_type(8)));
typedef float f32x4 __attribute__((ext_vector_type(4)));
typedef _Float16 f16x4 __attribute__((ext_vector_type(4)));

// ---------- zero-init of out (atomic accumulation target) ----------
__global__ void zero_out_kernel(float4* __restrict__ out4, int n4) {
    int i = blockIdx.x * blockDim.x + threadIdx.x;
    if (i < n4) out4[i] = make_float4(0.f, 0.f, 0.f, 0.f);
}

// ---------- fp32 -> f16 convert (core + padded weights), grid-stride ----------
// chunk = 8 floats in (32B), 8 halves out (16B).
__global__ void convert_f16(const float* __restrict__ core,
                            const float* __restrict__ wts,
                            _Float16* __restrict__ A16,
                            _Float16* __restrict__ W16,
                            int na8, int nw8, int w_src) {
    int total = na8 + nw8;
    for (int i = blockIdx.x * blockDim.x + threadIdx.x; i < total;
         i += gridDim.x * blockDim.x) {
        const float* src;
        _Float16* dst;
        bool valid;
        if (i < na8) {
            src = core + (size_t)i * 8;
            dst = A16 + (size_t)i * 8;
            valid = true;
        } else {
            int j = i - na8;
            src = wts + (size_t)j * 8;
            dst = W16 + (size_t)j * 8;
            valid = (j * 8 < w_src);   // w_src % 8 == 0
        }
        float f[8] = {0, 0, 0, 0, 0, 0, 0, 0};
        if (valid) {
            float4 v0 = ((const float4*)src)[0];
            float4 v1 = ((const float4*)src)[1];
            f[0] = v0.x; f[1] = v0.y; f[2] = v0.z; f[3] = v0.w;
            f[4] = v1.x; f[5] = v1.y; f[6] = v1.z; f[7] = v1.w;
        }
        f16x8 h;
#pragma unroll
        for (int j = 0; j < 8; ++j) h[j] = (_Float16)f[j];   // fptrunc = RNE
        *(f16x8*)dst = h;
    }
}

// ---------- async global->LDS, width 16 (literal) ----------
__device__ inline void load_lds16(const _Float16* g, _Float16* l) {
    __builtin_amdgcn_global_load_lds(
        (const __attribute__((address_space(1))) unsigned int*)(const void*)g,
        (__attribute__((address_space(3))) unsigned int*)(void*)l, 16, 0, 0);
}

// ---------- 1-term f16 GEMM, 128x128 tile, dbuf 2ph, swizzled LDS, split-K x4 ----
// LDS row r (128B): logical chunks 0-3 = A row r k-window, 4-7 = B row r.
// Physical slot = chunk ^ (r&7); written via pre-swizzled global SOURCE
// (linear global_load_lds dest), read with the same XOR. Measured 0 conflicts (R3).
__launch_bounds__(256, 4)
__global__ void gemm_f16_kernel(const _Float16* __restrict__ A16,
                                const _Float16* __restrict__ W16,
                                float* __restrict__ out) {
    __shared__ __align__(16) _Float16 sAB[2][BM * 64];   // 2 x 16 KB

    const int tid  = threadIdx.x;
    const int lane = tid & 63;
    const int wid  = tid >> 6;
    const int wr   = wid >> 1;   // 0..1 (row half)
    const int wc   = wid & 1;    // 0..1 (col half)

    // XCD-chunked bijective swizzle: 1024 blocks, 128 consecutive per XCD.
    int bid = blockIdx.x;
    int swz = (bid & 7) * 128 + (bid >> 3);
    const int colb = swz & 7;          // 8 col-blocks (fastest -> A-panel L2 reuse)
    const int ks   = (swz >> 3) & 3;   // 4 K-slices
    const int rowb = swz >> 5;         // 32 row-blocks
    const int brow = rowb * BM;
    const int bcol = colb * BN;
    const int kbeg = ks * (K_DIM / KSPLIT);
    const int NT   = (K_DIM / KSPLIT) / BK;   // 32 K-steps

    // Staging: 1024 16B chunks per K-step tile, 4 per thread. Dest LINEAR,
    // source pre-swizzled.
    const _Float16* src[4];
    int dstOff[4];
#pragma unroll
    for (int i = 0; i < 4; ++i) {
        int s = tid + 256 * i;          // slot 0..1023
        int r = s >> 3;                 // row 0..127
        int clog = (s & 7) ^ (r & 7);   // logical chunk stored at this slot
        dstOff[i] = s * 8;              // f16 offset (16B chunks)
        if (clog < 4)
            src[i] = A16 + (size_t)(brow + r) * K_DIM + kbeg + clog * 8;
        else
            src[i] = W16 + (size_t)(bcol + r) * K_DIM + kbeg + (clog - 4) * 8;
    }

    f32x4 acc[4][4] = {};

    // read-side swizzle: frag rows have row&7 == lr&7 (m*16, wr*64 are 0 mod 8)
    const int lr = lane & 15;
    const int hk = lane >> 4;                  // k-chunk 0..3
    const int xa = (hk ^ (lr & 7)) * 8;        // A chunk slot offset (f16)
    const int xb = xa ^ 32;                    // B: logical chunk |4 -> slot^4

#define STAGE(buf, koff)                                        \
    {                                                           \
        _Pragma("unroll")                                       \
        for (int i = 0; i < 4; ++i)                             \
            load_lds16(src[i] + (koff), &sAB[buf][dstOff[i]]);  \
    }

    STAGE(0, 0);
    __syncthreads();
    int cur = 0;

    for (int t = 0; t < NT; ++t) {
        if (t + 1 < NT) STAGE(cur ^ 1, (t + 1) * BK);

        f16x8 a[4], b[4];
#pragma unroll
        for (int m = 0; m < 4; ++m) {
            int r = wr * 64 + m * 16 + lr;
            a[m] = *(const f16x8*)&sAB[cur][r * 64 + xa];
        }
#pragma unroll
        for (int n = 0; n < 4; ++n) {
            int r = wc * 64 + n * 16 + lr;
            b[n] = *(const f16x8*)&sAB[cur][r * 64 + xb];
        }

#pragma unroll
        for (int m = 0; m < 4; ++m)
#pragma unroll
            for (int n = 0; n < 4; ++n)
                acc[m][n] = __builtin_amdgcn_mfma_f32_16x16x32_f16(a[m], b[n], acc[m][n], 0, 0, 0);

        __syncthreads();
        cur ^= 1;
    }

    // Epilogue: C/D layout col=lane&15, row=(lane>>4)*4+j; split-K -> atomics.
#pragma unroll
    for (int m = 0; m < 4; ++m) {
        int r0 = brow + wr * 64 + m * 16 + hk * 4;
#pragma unroll
        for (int n = 0; n < 4; ++n) {
            int c = bcol + wc * 64 + n * 16 + lr;
            if (c < N_CLS) {
#pragma unroll
                for (int j = 0; j < 4; ++j)
                    atomicAdd(&out[(size_t)(r0 + j) * N_CLS + c], acc[m][n][j]);
            }
        }
    }
#undef STAGE
}

// ---------- fp32 fallback (only if ws too small) ----------
__global__ void fallback_gemm(const float* __restrict__ A, const float* __restrict__ W,
                              float* __restrict__ out) {
    __shared__ float sA[16][17];
    __shared__ float sW[16][17];
    int tx = threadIdx.x, ty = threadIdx.y;
    int row  = blockIdx.y * 16 + ty;
    int wrow = blockIdx.x * 16 + ty;
    float acc = 0.f;
    for (int k0 = 0; k0 < K_DIM; k0 += 16) {
        sA[ty][tx] = A[(size_t)row * K_DIM + k0 + tx];
        sW[ty][tx] = (wrow < N_CLS) ? W[(size_t)wrow * K_DIM + k0 + tx] : 0.f;
        __syncthreads();
#pragma unroll
        for (int kk = 0; kk < 16; ++kk) acc += sA[ty][kk] * sW[tx][kk];
        __syncthreads();
    }
    int col = blockIdx.x * 16 + tx;
    if (col < N_CLS) out[(size_t)row * N_CLS + col] = acc;
}

extern "C" void kernel_launch(void* const* d_in, const int* in_sizes, int n_in,
                              void* d_out, int out_size, void* d_ws, size_t ws_size,
                              hipStream_t stream) {
    const float* core    = (const float*)d_in[0];   // [4096][4096]
    const float* weights = (const float*)d_in[1];   // [1000][4096]
    float* out = (float*)d_out;                     // [4096][1000]

    const size_t A_ELEMS = (size_t)M_DIM * K_DIM;   // 16,777,216
    const size_t W_SRC   = (size_t)N_CLS * K_DIM;   //  4,096,000
    const size_t W_ELEMS = (size_t)N_PAD * K_DIM;   //  4,194,304
    const size_t need = (A_ELEMS + W_ELEMS) * sizeof(_Float16);   // ~42 MiB

    if (ws_size < need) {
        dim3 blk(16, 16), grd((N_CLS + 15) / 16, M_DIM / 16);
        fallback_gemm<<<grd, blk, 0, stream>>>(core, weights, out);
        return;
    }

    _Float16* A16 = (_Float16*)d_ws;
    _Float16* W16 = A16 + A_ELEMS;

    // 1) zero out (d_out poisoned each launch; atomics accumulate)
    int n4 = (M_DIM * N_CLS) / 4;                    // 1,024,000
    zero_out_kernel<<<(n4 + 255) / 256, 256, 0, stream>>>((float4*)out, n4);

    // 2) convert both inputs to f16 (weights padded to 1024 rows with zeros)
    int na8 = (int)(A_ELEMS / 8);                    // 2,097,152
    int nw8 = (int)(W_ELEMS / 8);                    //   524,288
    convert_f16<<<2048, 256, 0, stream>>>(core, weights, A16, W16,
                                          na8, nw8, (int)W_SRC);

    // 3) GEMM: 1024 blocks = (8 col) x (32 row) x (4 k-slices), 4 blocks/CU
    gemm_f16_kernel<<<(N_PAD / BN) * (M_DIM / BM) * KSPLIT, 256, 0, stream>>>(
        A16, W16, out);
}

// Round 7
// 159.976 us; speedup vs baseline: 1.5845x; 1.4047x over previous
//
#include <hip/hip_runtime.h>
#include <hip/hip_bf16.h>

// out[4096,1000] = core[4096,4096] @ weights[1000,4096]^T, fp32.
// R7: f16 single-term GEMM (validated R6). Epilogue lever: atomic split-K ->
//     partial buffers in ws + reduce kernel. KSPLIT=2, grid 512 (2 blocks/CU),
//     NT=64. K-loop/swizzle/staging identical to the proven R3/R6 structure.

#define M_DIM 4096
#define K_DIM 4096
#define N_CLS 1000
#define N_PAD 1024

#define BM 128
#define BN 128
#define BK 32
#define KSPLIT 2

typedef _Float16 f16x8 __attribute__((ext_vector_type(8)));
typedef float f32x4 __attribute__((ext_vector_type(4)));

// ---------- fp32 -> f16 convert (core + padded weights), grid-stride ----------
__global__ void convert_f16(const float* __restrict__ core,
                            const float* __restrict__ wts,
                            _Float16* __restrict__ A16,
                            _Float16* __restrict__ W16,
                            int na8, int nw8, int w_src) {
    int total = na8 + nw8;
    for (int i = blockIdx.x * blockDim.x + threadIdx.x; i < total;
         i += gridDim.x * blockDim.x) {
        const float* src;
        _Float16* dst;
        bool valid;
        if (i < na8) {
            src = core + (size_t)i * 8;
            dst = A16 + (size_t)i * 8;
            valid = true;
        } else {
            int j = i - na8;
            src = wts + (size_t)j * 8;
            dst = W16 + (size_t)j * 8;
            valid = (j * 8 < w_src);   // w_src % 8 == 0
        }
        float f[8] = {0, 0, 0, 0, 0, 0, 0, 0};
        if (valid) {
            float4 v0 = ((const float4*)src)[0];
            float4 v1 = ((const float4*)src)[1];
            f[0] = v0.x; f[1] = v0.y; f[2] = v0.z; f[3] = v0.w;
            f[4] = v1.x; f[5] = v1.y; f[6] = v1.z; f[7] = v1.w;
        }
        f16x8 h;
#pragma unroll
        for (int j = 0; j < 8; ++j) h[j] = (_Float16)f[j];   // fptrunc = RNE
        *(f16x8*)dst = h;
    }
}

// ---------- async global->LDS, width 16 (literal) ----------
__device__ inline void load_lds16(const _Float16* g, _Float16* l) {
    __builtin_amdgcn_global_load_lds(
        (const __attribute__((address_space(1))) unsigned int*)(const void*)g,
        (__attribute__((address_space(3))) unsigned int*)(void*)l, 16, 0, 0);
}

// ---------- f16 GEMM, 128x128 tile, dbuf 2ph, swizzled LDS, split-K x2 ----------
// LDS row r (128B): logical chunks 0-3 = A row r k-window, 4-7 = B row r.
// Physical slot = chunk ^ (r&7); written via pre-swizzled global SOURCE
// (linear global_load_lds dest), read with same XOR. Measured 0 conflicts (R3/R6).
// Epilogue: plain coalesced stores to per-slice partial buffers P[ks][4096][1024].
__launch_bounds__(256, 2)
__global__ void gemm_f16_kernel(const _Float16* __restrict__ A16,
                                const _Float16* __restrict__ W16,
                                float* __restrict__ P) {
    __shared__ __align__(16) _Float16 sAB[2][BM * 64];   // 2 x 16 KB

    const int tid  = threadIdx.x;
    const int lane = tid & 63;
    const int wid  = tid >> 6;
    const int wr   = wid >> 1;   // 0..1 (row half)
    const int wc   = wid & 1;    // 0..1 (col half)

    // XCD-chunked bijective swizzle: 512 blocks, 64 consecutive per XCD.
    int bid = blockIdx.x;
    int swz = (bid & 7) * 64 + (bid >> 3);
    const int colb = swz & 7;          // 8 col-blocks (fastest -> A-panel L2 reuse)
    const int ks   = (swz >> 3) & 1;   // 2 K-slices
    const int rowb = swz >> 4;         // 32 row-blocks
    const int brow = rowb * BM;
    const int bcol = colb * BN;
    const int kbeg = ks * (K_DIM / KSPLIT);
    const int NT   = (K_DIM / KSPLIT) / BK;   // 64 K-steps

    // Staging: 1024 16B chunks per K-step tile, 4 per thread. Dest LINEAR,
    // source pre-swizzled.
    const _Float16* src[4];
    int dstOff[4];
#pragma unroll
    for (int i = 0; i < 4; ++i) {
        int s = tid + 256 * i;          // slot 0..1023
        int r = s >> 3;                 // row 0..127
        int clog = (s & 7) ^ (r & 7);   // logical chunk stored at this slot
        dstOff[i] = s * 8;              // f16 offset (16B chunks)
        if (clog < 4)
            src[i] = A16 + (size_t)(brow + r) * K_DIM + kbeg + clog * 8;
        else
            src[i] = W16 + (size_t)(bcol + r) * K_DIM + kbeg + (clog - 4) * 8;
    }

    f32x4 acc[4][4] = {};

    // read-side swizzle: frag rows have row&7 == lr&7 (m*16, wr*64 are 0 mod 8)
    const int lr = lane & 15;
    const int hk = lane >> 4;                  // k-chunk 0..3
    const int xa = (hk ^ (lr & 7)) * 8;        // A chunk slot offset (f16)
    const int xb = xa ^ 32;                    // B: logical chunk |4 -> slot^4

#define STAGE(buf, koff)                                        \
    {                                                           \
        _Pragma("unroll")                                       \
        for (int i = 0; i < 4; ++i)                             \
            load_lds16(src[i] + (koff), &sAB[buf][dstOff[i]]);  \
    }

    STAGE(0, 0);
    __syncthreads();
    int cur = 0;

    for (int t = 0; t < NT; ++t) {
        if (t + 1 < NT) STAGE(cur ^ 1, (t + 1) * BK);

        f16x8 a[4], b[4];
#pragma unroll
        for (int m = 0; m < 4; ++m) {
            int r = wr * 64 + m * 16 + lr;
            a[m] = *(const f16x8*)&sAB[cur][r * 64 + xa];
        }
#pragma unroll
        for (int n = 0; n < 4; ++n) {
            int r = wc * 64 + n * 16 + lr;
            b[n] = *(const f16x8*)&sAB[cur][r * 64 + xb];
        }

#pragma unroll
        for (int m = 0; m < 4; ++m)
#pragma unroll
            for (int n = 0; n < 4; ++n)
                acc[m][n] = __builtin_amdgcn_mfma_f32_16x16x32_f16(a[m], b[n], acc[m][n], 0, 0, 0);

        __syncthreads();
        cur ^= 1;
    }

    // Epilogue: C/D layout col=lane&15, row=(lane>>4)*4+j.
    // Plain stores to this slice's partial buffer (padded to 1024 cols, no guard).
    float* Pk = P + (size_t)ks * M_DIM * N_PAD;
#pragma unroll
    for (int m = 0; m < 4; ++m) {
        int r0 = brow + wr * 64 + m * 16 + hk * 4;
#pragma unroll
        for (int n = 0; n < 4; ++n) {
            int c = bcol + wc * 64 + n * 16 + lr;
#pragma unroll
            for (int j = 0; j < 4; ++j)
                Pk[(size_t)(r0 + j) * N_PAD + c] = acc[m][n][j];
        }
    }
#undef STAGE
}

// ---------- reduce: out[4096][1000] = P[0] + P[1] (strip 1024->1000 pad) ------
__global__ void reduce_kernel(const float* __restrict__ P,
                              float* __restrict__ out, int n4out) {
    int i = blockIdx.x * blockDim.x + threadIdx.x;
    if (i >= n4out) return;
    int flat = i * 4;
    int row = flat / N_CLS;            // magic-mul div; 1000 % 4 == 0 so the 4
    int col = flat - row * N_CLS;      // elems stay within one row, col % 4 == 0
    size_t p = (size_t)row * N_PAD + col;
    float4 a = *(const float4*)&P[p];
    float4 b = *(const float4*)&P[(size_t)M_DIM * N_PAD + p];
    float4 r;
    r.x = a.x + b.x; r.y = a.y + b.y; r.z = a.z + b.z; r.w = a.w + b.w;
    *(float4*)&out[flat] = r;
}

// ---------- fp32 fallback (only if ws too small) ----------
__global__ void fallback_gemm(const float* __restrict__ A, const float* __restrict__ W,
                              float* __restrict__ out) {
    __shared__ float sA[16][17];
    __shared__ float sW[16][17];
    int tx = threadIdx.x, ty = threadIdx.y;
    int row  = blockIdx.y * 16 + ty;
    int wrow = blockIdx.x * 16 + ty;
    float acc = 0.f;
    for (int k0 = 0; k0 < K_DIM; k0 += 16) {
        sA[ty][tx] = A[(size_t)row * K_DIM + k0 + tx];
        sW[ty][tx] = (wrow < N_CLS) ? W[(size_t)wrow * K_DIM + k0 + tx] : 0.f;
        __syncthreads();
#pragma unroll
        for (int kk = 0; kk < 16; ++kk) acc += sA[ty][kk] * sW[tx][kk];
        __syncthreads();
    }
    int col = blockIdx.x * 16 + tx;
    if (col < N_CLS) out[(size_t)row * N_CLS + col] = acc;
}

extern "C" void kernel_launch(void* const* d_in, const int* in_sizes, int n_in,
                              void* d_out, int out_size, void* d_ws, size_t ws_size,
                              hipStream_t stream) {
    const float* core    = (const float*)d_in[0];   // [4096][4096]
    const float* weights = (const float*)d_in[1];   // [1000][4096]
    float* out = (float*)d_out;                     // [4096][1000]

    const size_t A_ELEMS = (size_t)M_DIM * K_DIM;   // 16,777,216
    const size_t W_SRC   = (size_t)N_CLS * K_DIM;   //  4,096,000
    const size_t W_ELEMS = (size_t)N_PAD * K_DIM;   //  4,194,304
    const size_t P_ELEMS = (size_t)KSPLIT * M_DIM * N_PAD;   // 8,388,608 f32
    const size_t need = (A_ELEMS + W_ELEMS) * sizeof(_Float16)
                      + P_ELEMS * sizeof(float);    // ~72 MiB

    if (ws_size < need) {
        dim3 blk(16, 16), grd((N_CLS + 15) / 16, M_DIM / 16);
        fallback_gemm<<<grd, blk, 0, stream>>>(core, weights, out);
        return;
    }

    _Float16* A16 = (_Float16*)d_ws;
    _Float16* W16 = A16 + A_ELEMS;
    float*    P   = (float*)(W16 + W_ELEMS);

    // 1) convert both inputs to f16 (weights padded to 1024 rows with zeros)
    int na8 = (int)(A_ELEMS / 8);                    // 2,097,152
    int nw8 = (int)(W_ELEMS / 8);                    //   524,288
    convert_f16<<<2048, 256, 0, stream>>>(core, weights, A16, W16,
                                          na8, nw8, (int)W_SRC);

    // 2) GEMM: 512 blocks = (8 col) x (32 row) x (2 k-slices), 2 blocks/CU.
    //    Writes partials to P (no atomics, no zero-init needed).
    gemm_f16_kernel<<<(N_PAD / BN) * (M_DIM / BM) * KSPLIT, 256, 0, stream>>>(
        A16, W16, P);

    // 3) reduce the 2 K-slices into out (strips the 1024->1000 col pad)
    int n4out = (M_DIM * N_CLS) / 4;                 // 1,024,000
    reduce_kernel<<<(n4out + 255) / 256, 256, 0, stream>>>(P, out, n4out);
}